// Round 1
// baseline (571.504 us; speedup 1.0000x reference)
//
#include <hip/hip_runtime.h>

// SNN forward: B=256 blocks (one per batch element), 384 threads (6 waves).
// Thread tid owns: LIF1 neuron j=tid (c=tid/24, p=tid%24)  AND
//                  FC partial (o=tid%48 [35 real + 13 pad], chunk=tid/48, 48 K-weights in VGPRs).
// Per step: conv from LDS-staged x -> mem1/spike -> spk broadcast via LDS ->
//           FC partials (ds_read_b128 of spikes, register weights) -> LDS reduce ->
//           wave0 lanes 0..34 update mem2 + accumulate mean.

#define BN   256
#define TN   1000
#define LN   30
#define KW   7
#define LO   24
#define JN   384   // 16*24 flattened spike dim
#define OC   35
#define OP   48    // padded output count (384/48 = 8 chunks)
#define NCH  8
#define CHJ  48    // K elements per chunk
#define TT   250   // timesteps of x staged per LDS chunk

__global__ __launch_bounds__(384) void snn_fwd(
    const float* __restrict__ x,      // (256,1000,30)
    const float* __restrict__ conv_w, // (16,1,7)
    const float* __restrict__ conv_b, // (16)
    const float* __restrict__ fc_w,   // (35,384)
    const float* __restrict__ fc_b,   // (35)
    float* __restrict__ out)          // (256,35)
{
    __shared__ float xs[TT * LN];        // 30 KB
    __shared__ float spk[JN];            // 1.5 KB
    __shared__ float part[NCH * OP];     // 1.5 KB

    const int tid = threadIdx.x;
    const int b   = blockIdx.x;

    const int c  = tid / LO;   // conv channel
    const int p  = tid % LO;   // conv position
    const int o  = tid % OP;   // fc output (o>=35 -> dead weight lanes)
    const int ch = tid / OP;   // fc K-chunk

    // conv weights for this thread's channel (registers)
    float cw[KW];
#pragma unroll
    for (int k = 0; k < KW; ++k) cw[k] = conv_w[c * KW + k];
    const float cb = conv_b[c];

    // fc weights for (o, chunk) (registers; zero for pad lanes)
    float w[CHJ];
#pragma unroll
    for (int i = 0; i < CHJ; ++i)
        w[i] = (o < OC) ? fc_w[o * JN + ch * CHJ + i] : 0.0f;

    const float fcb = (tid < OC) ? fc_b[tid] : 0.0f;

    float mem1 = 0.0f, sp = 0.0f;       // LIF1 state (per neuron)
    float mem2 = 0.0f, acc_out = 0.0f;  // LIF2 state (lanes 0..34 only)

    const float* xb = x + (size_t)b * TN * LN;

#pragma unroll 1
    for (int t = 0; t < TN; ++t) {
        if ((t % TT) == 0) {
            __syncthreads();   // all prior xs readers done (their reads precede their barriers)
            const float* src = xb + t * LN;
#pragma unroll 1
            for (int i = tid; i < TT * LN; i += 384) xs[i] = src[i];
            __syncthreads();
        }
        const int tl = t % TT;

        // ---- conv1d (valid, 7 taps) ----
        float c1 = cb;
        const float* xr = &xs[tl * LN + p];
#pragma unroll
        for (int k = 0; k < KW; ++k) c1 = fmaf(cw[k], xr[k], c1);

        // ---- LIF1: reset-by-subtraction with previous spike, then new spike ----
        mem1 = 0.9f * mem1 + c1 - sp;
        sp = (mem1 > 1.0f) ? 1.0f : 0.0f;
        spk[tid] = sp;
        __syncthreads();                       // barrier A: spikes visible

        // ---- FC partial: 48 MACs, spikes from LDS (b128 broadcast), weights in regs ----
        float acc = 0.0f;
        const float4* s4 = (const float4*)&spk[ch * CHJ];
#pragma unroll
        for (int i = 0; i < CHJ / 4; ++i) {
            float4 v = s4[i];
            acc = fmaf(v.x, w[4 * i + 0], acc);
            acc = fmaf(v.y, w[4 * i + 1], acc);
            acc = fmaf(v.z, w[4 * i + 2], acc);
            acc = fmaf(v.w, w[4 * i + 3], acc);
        }
        part[ch * OP + o] = acc;
        __syncthreads();                       // barrier B: partials visible

        // ---- reduce + LIF2 (wave 0, lanes 0..34; overlaps next step's conv on other waves) ----
        if (tid < OC) {
            float c2 = fcb;
#pragma unroll
            for (int q = 0; q < NCH; ++q) c2 += part[q * OP + tid];
            float r2 = (mem2 > 1.0f) ? 1.0f : 0.0f;
            mem2 = 0.9f * mem2 + c2 - r2;
            acc_out += mem2;
        }
    }

    if (tid < OC) out[b * OC + tid] = acc_out * (1.0f / (float)TN);
}

extern "C" void kernel_launch(void* const* d_in, const int* in_sizes, int n_in,
                              void* d_out, int out_size, void* d_ws, size_t ws_size,
                              hipStream_t stream) {
    const float* x      = (const float*)d_in[0];
    const float* conv_w = (const float*)d_in[1];
    const float* conv_b = (const float*)d_in[2];
    const float* fc_w   = (const float*)d_in[3];
    const float* fc_b   = (const float*)d_in[4];
    float* out          = (float*)d_out;

    snn_fwd<<<BN, 384, 0, stream>>>(x, conv_w, conv_b, fc_w, fc_b, out);
}

// Round 3
// 227.455 us; speedup vs baseline: 2.5126x; 2.5126x over previous
//
#include <hip/hip_runtime.h>

typedef _Float16 half8 __attribute__((ext_vector_type(8)));
typedef float f32x4 __attribute__((ext_vector_type(4)));

#define SPH   32          // timesteps per phase
#define NPH   33          // 32 compute phases + 1 drain phase
#define SPKW  776         // spkL row stride in f16 (768 data + 8 pad -> 16B aligned, 4-bank row shift)
#define XSW   32          // xs row stride (floats)
#define C2W   48          // c2L row stride (floats) — MUST be >= 48: wave m=2 writes cols 32..47
#define TN    1000

// 384 threads = 6 waves.
// waves 0-2 (192 thr): conv+LIF1. thread = (g=ct/24, p=ct%24), owns channels g and g+8.
// waves 3-5: FC GEMM via mfma_f32_16x16x32_f16, M-tile m = wid-3 (outputs m*16..+15, padded to 48).
// wave 3 lanes 0..34: sequential LIF2 scan + output accumulation.
// K = 768: [0,384) = f16(w) * spike(0/1); [384,768) = f16((w-hi)*512) * spike/512  (split-f16, ~exact).
__global__ __launch_bounds__(384) void snn_fwd(
    const float* __restrict__ x,      // (256,1000,30)
    const float* __restrict__ conv_w, // (16,1,7)
    const float* __restrict__ conv_b, // (16)
    const float* __restrict__ fc_w,   // (35,384)
    const float* __restrict__ fc_b,   // (35)
    float* __restrict__ out)          // (256,35)
{
    __shared__ _Float16 spkL[SPH][SPKW];   // 49664 B
    __shared__ float    xs[SPH][XSW];      //  4096 B
    __shared__ float    c2L[SPH][C2W];     //  6144 B

    const int tid  = threadIdx.x;
    const int b    = blockIdx.x;
    const int wid  = tid >> 6;
    const int lane = tid & 63;

    // ---------- conv-wave setup ----------
    const int ct  = tid;          // 0..191 when wid<3
    const int g   = ct / 24;
    const int p   = ct % 24;
    const int par = p & 1;
    const int pe  = p - par;      // even window base; taps shifted into weights

    float wk0[8], wk1[8];
    float cb0 = 0.f, cb1 = 0.f;
    if (wid < 3) {
        const int c0 = g, c1 = g + 8;
#pragma unroll
        for (int j = 0; j < 8; ++j) {
            int k = j - par;
            bool in = (k >= 0) && (k < 7);
            wk0[j] = in ? conv_w[c0 * 7 + k] : 0.f;
            wk1[j] = in ? conv_w[c1 * 7 + k] : 0.f;
        }
        cb0 = conv_b[c0];
        cb1 = conv_b[c1];
    }

    // ---------- FC-wave setup: preload A fragments (weights, split f16) ----------
    const int m  = wid - 3;
    const int nL = lane & 15;     // A row (o_local) at load; B col (t_local); C col
    const int q  = lane >> 4;     // quad: k = q*8 + j
    half8 A[24];
    if (wid >= 3) {
        const int o = m * 16 + nL;
#pragma unroll
        for (int kt = 0; kt < 24; ++kt) {
            half8 a;
#pragma unroll
            for (int j = 0; j < 8; ++j) {
                int K = kt * 32 + q * 8 + j;
                _Float16 av = (_Float16)0.f;
                if (o < 35) {
                    if (K < 384) {
                        av = (_Float16)fc_w[o * 384 + K];
                    } else {
                        float v = fc_w[o * 384 + (K - 384)];
                        _Float16 h = (_Float16)v;
                        av = (_Float16)((v - (float)h) * 512.0f);
                    }
                }
                a[j] = av;
            }
            A[kt] = a;
        }
    }

    const float fcb = (wid == 3 && lane < 35) ? fc_b[lane] : 0.f;

    // ---------- state ----------
    float m10 = 0.f, m11 = 0.f, sp0 = 0.f, sp1 = 0.f;   // LIF1 (conv threads)
    float mem2 = 0.f, accO = 0.f;                        // LIF2 (wave3 lanes<35)

    const float* xb = x + (size_t)b * (TN * 30);

#pragma unroll 1
    for (int ph = 0; ph < NPH; ++ph) {
        const int t0 = ph * SPH;

        // ================= segment 1: stage x(ph) | GEMM spikes(ph-1) =================
        if (wid < 3) {
            if (ph < 32) {
#pragma unroll
                for (int r = 0; r < 5; ++r) {
                    int f = ct + 192 * r;        // 0..959
                    int s = f / 30, l = f % 30;
                    int t = t0 + s;
                    xs[s][l] = (t < TN) ? xb[t * 30 + l] : 0.f;
                }
            }
        } else if (ph > 0) {
            f32x4 acc0 = {0.f, 0.f, 0.f, 0.f};
            f32x4 acc1 = {0.f, 0.f, 0.f, 0.f};
#pragma unroll
            for (int kt = 0; kt < 24; ++kt) {
                const half8 b0 = *(const half8*)&spkL[nL][kt * 32 + q * 8];
                const half8 b1 = *(const half8*)&spkL[16 + nL][kt * 32 + q * 8];
                acc0 = __builtin_amdgcn_mfma_f32_16x16x32_f16(A[kt], b0, acc0, 0, 0, 0);
                acc1 = __builtin_amdgcn_mfma_f32_16x16x32_f16(A[kt], b1, acc1, 0, 0, 0);
            }
            // C/D: col = lane&15 (t_local), row = q*4 + i (o_local)
#pragma unroll
            for (int i = 0; i < 4; ++i) {
                c2L[nL][m * 16 + q * 4 + i]      = acc0[i];
                c2L[16 + nL][m * 16 + q * 4 + i] = acc1[i];
            }
        }
        __syncthreads();

        // ================= segment 2: conv+LIF1(ph) -> spikes | LIF2 scan(ph-1) =================
        if (wid < 3) {
            if (ph < 32) {
#pragma unroll 4
                for (int s = 0; s < SPH; ++s) {
                    const float2* x2 = (const float2*)&xs[s][pe];
                    float2 f0 = x2[0], f1 = x2[1], f2 = x2[2], f3 = x2[3];
                    float c1a = cb0, c1b = cb1;
                    c1a = fmaf(wk0[0], f0.x, c1a);  c1b = fmaf(wk1[0], f0.x, c1b);
                    c1a = fmaf(wk0[1], f0.y, c1a);  c1b = fmaf(wk1[1], f0.y, c1b);
                    c1a = fmaf(wk0[2], f1.x, c1a);  c1b = fmaf(wk1[2], f1.x, c1b);
                    c1a = fmaf(wk0[3], f1.y, c1a);  c1b = fmaf(wk1[3], f1.y, c1b);
                    c1a = fmaf(wk0[4], f2.x, c1a);  c1b = fmaf(wk1[4], f2.x, c1b);
                    c1a = fmaf(wk0[5], f2.y, c1a);  c1b = fmaf(wk1[5], f2.y, c1b);
                    c1a = fmaf(wk0[6], f3.x, c1a);  c1b = fmaf(wk1[6], f3.x, c1b);
                    c1a = fmaf(wk0[7], f3.y, c1a);  c1b = fmaf(wk1[7], f3.y, c1b);

                    m10 = 0.9f * m10 + c1a - sp0;
                    sp0 = (m10 > 1.0f) ? 1.0f : 0.0f;
                    m11 = 0.9f * m11 + c1b - sp1;
                    sp1 = (m11 > 1.0f) ? 1.0f : 0.0f;

                    spkL[s][ct]             = (_Float16)sp0;
                    spkL[s][ct + 192]       = (_Float16)sp1;
                    spkL[s][384 + ct]       = (_Float16)(sp0 * (1.0f / 512.0f));
                    spkL[s][384 + ct + 192] = (_Float16)(sp1 * (1.0f / 512.0f));
                }
            }
        } else if (wid == 3 && lane < 35 && ph > 0) {
            const int tb = t0 - SPH;
#pragma unroll 4
            for (int s = 0; s < SPH; ++s) {
                float c2 = c2L[s][lane] + fcb;
                float r2 = (mem2 > 1.0f) ? 1.0f : 0.0f;
                mem2 = 0.9f * mem2 + c2 - r2;
                if (tb + s < TN) accO += mem2;
            }
        }
        __syncthreads();
    }

    if (wid == 3 && lane < 35) out[b * 35 + lane] = accO * (1.0f / (float)TN);
}

extern "C" void kernel_launch(void* const* d_in, const int* in_sizes, int n_in,
                              void* d_out, int out_size, void* d_ws, size_t ws_size,
                              hipStream_t stream) {
    const float* x      = (const float*)d_in[0];
    const float* conv_w = (const float*)d_in[1];
    const float* conv_b = (const float*)d_in[2];
    const float* fc_w   = (const float*)d_in[3];
    const float* fc_b   = (const float*)d_in[4];
    float* out          = (float*)d_out;

    snn_fwd<<<256, 384, 0, stream>>>(x, conv_w, conv_b, fc_w, fc_b, out);
}

// Round 4
// 178.068 us; speedup vs baseline: 3.2095x; 1.2773x over previous
//
#include <hip/hip_runtime.h>

typedef _Float16 half8 __attribute__((ext_vector_type(8)));
typedef float f32x4 __attribute__((ext_vector_type(4)));

#define SPH  32           // timesteps per phase
#define NPH  33           // 32 compute phases + 1 drain
#define SPKW 392          // spkL row stride f16: 384 + 8 pad (784 B rows, 16B aligned)
#define XSW  32           // xs row stride (floats)
#define C2W  48           // c2L row stride (floats); wave m=2 writes cols 32..47
#define TN   1000

// 384 threads = 6 waves.
// waves 0-2 (ct=tid 0..191): conv+LIF1, thread = (c=ct/12, u=ct%12) -> positions 2u,2u+1.
//   Two 7-tap windows share 8 xs floats (4 ds_read_b64); spikes bit-packed, 1 ds_write_b32.
//   Also stage x(ph+1): global loads issued in seg1 (regs), stored to xs[(ph+1)&1] end of seg2.
// waves 3-5: FC GEMM (K=384, f16 weights) via mfma_f32_16x16x32_f16, M-tile m=wid-3.
//   All 24 B-fragments preloaded (regs free after dropping split-K) -> pipelined LDS reads.
// wave 3 lanes 0..34: sequential LIF2 scan (seg2) + output accumulation.
__global__ __launch_bounds__(384) void snn_fwd(
    const float* __restrict__ x,      // (256,1000,30)
    const float* __restrict__ conv_w, // (16,1,7)
    const float* __restrict__ conv_b, // (16)
    const float* __restrict__ fc_w,   // (35,384)
    const float* __restrict__ fc_b,   // (35)
    float* __restrict__ out)          // (256,35)
{
    __shared__ _Float16 spkL[SPH][SPKW];   // 25088 B
    __shared__ float    xs[2][SPH][XSW];   //  8192 B
    __shared__ float    c2L[SPH][C2W];     //  6144 B

    const int tid  = threadIdx.x;
    const int b    = blockIdx.x;
    const int wid  = tid >> 6;
    const int lane = tid & 63;

    // ---------- conv-wave setup ----------
    const int ct = tid;          // 0..191 when wid<3
    const int c  = ct / 12;      // channel
    const int u  = ct % 12;      // position pair: p = 2u, 2u+1
    float wk[7];
    float cb = 0.f;
    if (wid < 3) {
#pragma unroll
        for (int k = 0; k < 7; ++k) wk[k] = conv_w[c * 7 + k];
        cb = conv_b[c];
    }

    // ---------- FC-wave setup: A fragments (f16 weights, K=384) ----------
    const int m  = wid - 3;
    const int nL = lane & 15;    // B col (t_local); C col
    const int q  = lane >> 4;    // quad: k = q*8 + j
    half8 A[12];
    if (wid >= 3) {
        const int o = m * 16 + nL;
#pragma unroll
        for (int kt = 0; kt < 12; ++kt) {
            half8 a;
#pragma unroll
            for (int j = 0; j < 8; ++j) {
                int K = kt * 32 + q * 8 + j;
                a[j] = (o < 35) ? (_Float16)fc_w[o * 384 + K] : (_Float16)0.f;
            }
            A[kt] = a;
        }
    }
    const float fcb = (wid == 3 && lane < 35) ? fc_b[lane] : 0.f;

    // ---------- state ----------
    float m10 = 0.f, m11 = 0.f, sp0 = 0.f, sp1 = 0.f;   // LIF1
    float mem2 = 0.f, accO = 0.f;                        // LIF2 (wave3 lanes<35)

    const float* xb = x + (size_t)b * (TN * 30);

    // ---------- prologue: stage xs[0] for ph=0 (960 floats = 192 thr * 5) ----------
    if (wid < 3) {
#pragma unroll
        for (int r = 0; r < 5; ++r) {
            int f = ct + 192 * r;          // 0..959
            xs[0][f / 30][f % 30] = xb[f]; // t = f/30 < 32 < TN
        }
    }
    __syncthreads();

#pragma unroll 1
    for (int ph = 0; ph < NPH; ++ph) {
        float xr[5];

        // ================= segment 1: GEMM(ph-1) | issue x loads for ph+1 =================
        if (wid < 3) {
            if (ph < NPH - 2) {            // stage for ph+1 in 1..31
                const float* src = xb + (ph + 1) * (SPH * 30);
#pragma unroll
                for (int r = 0; r < 5; ++r) {
                    int f = ct + 192 * r;
                    int t = (ph + 1) * SPH + f / 30;
                    xr[r] = (t < TN) ? src[f] : 0.f;
                }
            }
        } else if (ph > 0) {
            half8 B0[12], B1[12];
#pragma unroll
            for (int kt = 0; kt < 12; ++kt) {
                B0[kt] = *(const half8*)&spkL[nL][kt * 32 + q * 8];
                B1[kt] = *(const half8*)&spkL[16 + nL][kt * 32 + q * 8];
            }
            f32x4 acc0 = {0.f, 0.f, 0.f, 0.f};
            f32x4 acc1 = {0.f, 0.f, 0.f, 0.f};
#pragma unroll
            for (int kt = 0; kt < 12; ++kt) {
                acc0 = __builtin_amdgcn_mfma_f32_16x16x32_f16(A[kt], B0[kt], acc0, 0, 0, 0);
                acc1 = __builtin_amdgcn_mfma_f32_16x16x32_f16(A[kt], B1[kt], acc1, 0, 0, 0);
            }
            // C/D: col = lane&15 (t_local), row = q*4+i (o_local)
            *(f32x4*)&c2L[nL][m * 16 + q * 4]      = acc0;
            *(f32x4*)&c2L[16 + nL][m * 16 + q * 4] = acc1;
        }
        __syncthreads();

        // ================= segment 2: conv+LIF1(ph) | scan(ph-1) | xs stores =================
        if (wid < 3) {
            if (ph < NPH - 1) {
                const float* xrow = &xs[ph & 1][0][2 * u];
#pragma unroll 4
                for (int s = 0; s < SPH; ++s) {
                    const float2* x2 = (const float2*)(xrow + s * XSW);
                    float2 a0 = x2[0], a1 = x2[1], a2 = x2[2], a3 = x2[3];
                    float c1a = cb, c1b = cb;
                    c1a = fmaf(wk[0], a0.x, c1a);  c1b = fmaf(wk[0], a0.y, c1b);
                    c1a = fmaf(wk[1], a0.y, c1a);  c1b = fmaf(wk[1], a1.x, c1b);
                    c1a = fmaf(wk[2], a1.x, c1a);  c1b = fmaf(wk[2], a1.y, c1b);
                    c1a = fmaf(wk[3], a1.y, c1a);  c1b = fmaf(wk[3], a2.x, c1b);
                    c1a = fmaf(wk[4], a2.x, c1a);  c1b = fmaf(wk[4], a2.y, c1b);
                    c1a = fmaf(wk[5], a2.y, c1a);  c1b = fmaf(wk[5], a3.x, c1b);
                    c1a = fmaf(wk[6], a3.x, c1a);  c1b = fmaf(wk[6], a3.y, c1b);

                    m10 = fmaf(0.9f, m10, c1a - sp0);
                    m11 = fmaf(0.9f, m11, c1b - sp1);
                    sp0 = (m10 > 1.0f) ? 1.0f : 0.0f;
                    sp1 = (m11 > 1.0f) ? 1.0f : 0.0f;
                    unsigned pk = (m10 > 1.0f ? 0x3C00u : 0u) | (m11 > 1.0f ? 0x3C000000u : 0u);
                    *(unsigned*)&spkL[s][2 * ct] = pk;
                }
            }
            if (ph < NPH - 2) {
                float* dst = &xs[(ph + 1) & 1][0][0];
#pragma unroll
                for (int r = 0; r < 5; ++r) {
                    int f = ct + 192 * r;
                    dst[(f / 30) * XSW + (f % 30)] = xr[r];
                }
            }
        } else if (wid == 3 && lane < 35 && ph > 0) {
            const int tb = (ph - 1) * SPH;
#pragma unroll
            for (int s8 = 0; s8 < SPH; s8 += 8) {
                float v[8];
#pragma unroll
                for (int j = 0; j < 8; ++j) v[j] = c2L[s8 + j][lane] + fcb;
#pragma unroll
                for (int j = 0; j < 8; ++j) {
                    float r2 = (mem2 > 1.0f) ? 1.0f : 0.0f;
                    mem2 = 0.9f * mem2 + v[j] - r2;
                    if (tb + s8 + j < TN) accO += mem2;
                }
            }
        }
        __syncthreads();
    }

    if (wid == 3 && lane < 35) out[b * 35 + lane] = accO * (1.0f / (float)TN);
}

extern "C" void kernel_launch(void* const* d_in, const int* in_sizes, int n_in,
                              void* d_out, int out_size, void* d_ws, size_t ws_size,
                              hipStream_t stream) {
    const float* x      = (const float*)d_in[0];
    const float* conv_w = (const float*)d_in[1];
    const float* conv_b = (const float*)d_in[2];
    const float* fc_w   = (const float*)d_in[3];
    const float* fc_b   = (const float*)d_in[4];
    float* out          = (float*)d_out;

    snn_fwd<<<256, 384, 0, stream>>>(x, conv_w, conv_b, fc_w, fc_b, out);
}

// Round 5
// 169.079 us; speedup vs baseline: 3.3801x; 1.0532x over previous
//
#include <hip/hip_runtime.h>

typedef _Float16 half8 __attribute__((ext_vector_type(8)));
typedef float f32x4 __attribute__((ext_vector_type(4)));

#define SPH  32           // timesteps per phase
#define NIT  34           // 32 compute phases + 2 pipeline-drain iterations
#define SPKW 392          // spk row stride f16: 384 + 8 pad (784 B rows; +4 banks/row)
#define XSW  32           // xs row stride (floats)
#define C2W  48           // c2L row stride (floats); wave m=2 writes cols 32..47
#define TN   1000

// Software-pipelined, ONE barrier per iteration. At iteration ph:
//   waves 0-2: conv+LIF1(ph)  [reads xs[ph&1], writes spk[ph&1]] + stage xs(ph+1)
//   waves 3-5: FC GEMM(ph-1)  [reads spk[(ph-1)&1], writes c2L[(ph-1)&1]]
//   wave 3:    LIF2 scan(ph-2) [reads c2L[(ph-2)&1]]
// Every producer->consumer pair is separated by exactly one __syncthreads();
// every buffer rewrite by two. Pipeline depth 2 -> NIT = 32 + 2.
__global__ __launch_bounds__(384) void snn_fwd(
    const float* __restrict__ x,      // (256,1000,30)
    const float* __restrict__ conv_w, // (16,1,7)
    const float* __restrict__ conv_b, // (16)
    const float* __restrict__ fc_w,   // (35,384)
    const float* __restrict__ fc_b,   // (35)
    float* __restrict__ out)          // (256,35)
{
    __shared__ _Float16 spk[2][SPH][SPKW];   // 50176 B
    __shared__ float    xs[2][SPH][XSW];     //  8192 B
    __shared__ float    c2L[2][SPH][C2W];    // 12288 B

    const int tid  = threadIdx.x;
    const int b    = blockIdx.x;
    const int wid  = tid >> 6;
    const int lane = tid & 63;

    // ---------- conv-wave setup: thread = (c=ct/12, u=ct%12) -> positions 2u,2u+1 ----------
    const int ct = tid;          // 0..191 when wid<3
    const int c  = ct / 12;
    const int u  = ct % 12;
    float wk[7];
    float cb = 0.f;
    if (wid < 3) {
#pragma unroll
        for (int k = 0; k < 7; ++k) wk[k] = conv_w[c * 7 + k];
        cb = conv_b[c];
    }

    // ---------- FC-wave setup: A fragments (f16 weights, K=384) ----------
    const int m  = wid - 3;
    const int nL = lane & 15;    // B col (t_local); C col
    const int q  = lane >> 4;    // quad: k = q*8 + j
    half8 A[12];
    if (wid >= 3) {
        const int o = m * 16 + nL;
#pragma unroll
        for (int kt = 0; kt < 12; ++kt) {
            half8 a;
#pragma unroll
            for (int j = 0; j < 8; ++j) {
                int K = kt * 32 + q * 8 + j;
                a[j] = (o < 35) ? (_Float16)fc_w[o * 384 + K] : (_Float16)0.f;
            }
            A[kt] = a;
        }
    }
    const float fcb = (wid == 3 && lane < 35) ? fc_b[lane] : 0.f;

    // ---------- state ----------
    float m10 = 0.f, m11 = 0.f, sp0 = 0.f, sp1 = 0.f;   // LIF1
    float mem2 = 0.f, accO = 0.f;                        // LIF2 (wave3 lanes<35)

    const float* xb = x + (size_t)b * (TN * 30);

    // ---------- prologue: stage xs[0] (960 floats = 192 thr * 5) ----------
    if (wid < 3) {
#pragma unroll
        for (int r = 0; r < 5; ++r) {
            int f = ct + 192 * r;          // 0..959
            xs[0][f / 30][f % 30] = xb[f]; // t < 32 < TN
        }
    }
    __syncthreads();

#pragma unroll 1
    for (int ph = 0; ph < NIT; ++ph) {
        if (wid < 3) {
            float xr[5];
            const bool stg = (ph <= 30);
            if (stg) {                     // issue global loads early (latency overlap)
                const float* src = xb + (ph + 1) * (SPH * 30);
#pragma unroll
                for (int r = 0; r < 5; ++r) {
                    int f = ct + 192 * r;
                    int t = (ph + 1) * SPH + f / 30;
                    xr[r] = (t < TN) ? src[f] : 0.f;
                }
            }
            if (ph < 32) {
                const float* xrow = &xs[ph & 1][0][2 * u];
                _Float16* sdst = &spk[ph & 1][0][2 * ct];
#pragma unroll 4
                for (int s = 0; s < SPH; ++s) {
                    const float2* x2 = (const float2*)(xrow + s * XSW);
                    float2 a0 = x2[0], a1 = x2[1], a2 = x2[2], a3 = x2[3];
                    float c1a = cb, c1b = cb;
                    c1a = fmaf(wk[0], a0.x, c1a);  c1b = fmaf(wk[0], a0.y, c1b);
                    c1a = fmaf(wk[1], a0.y, c1a);  c1b = fmaf(wk[1], a1.x, c1b);
                    c1a = fmaf(wk[2], a1.x, c1a);  c1b = fmaf(wk[2], a1.y, c1b);
                    c1a = fmaf(wk[3], a1.y, c1a);  c1b = fmaf(wk[3], a2.x, c1b);
                    c1a = fmaf(wk[4], a2.x, c1a);  c1b = fmaf(wk[4], a2.y, c1b);
                    c1a = fmaf(wk[5], a2.y, c1a);  c1b = fmaf(wk[5], a3.x, c1b);
                    c1a = fmaf(wk[6], a3.x, c1a);  c1b = fmaf(wk[6], a3.y, c1b);

                    m10 = fmaf(0.9f, m10, c1a - sp0);
                    m11 = fmaf(0.9f, m11, c1b - sp1);
                    sp0 = (m10 > 1.0f) ? 1.0f : 0.0f;
                    sp1 = (m11 > 1.0f) ? 1.0f : 0.0f;
                    unsigned pk = (m10 > 1.0f ? 0x3C00u : 0u) | (m11 > 1.0f ? 0x3C000000u : 0u);
                    *(unsigned*)(sdst + s * SPKW) = pk;
                }
            }
            if (stg) {                     // store staged x into the other buffer
                float* dst = &xs[(ph + 1) & 1][0][0];
#pragma unroll
                for (int r = 0; r < 5; ++r) {
                    int f = ct + 192 * r;
                    dst[(f / 30) * XSW + (f % 30)] = xr[r];
                }
            }
        } else {
            if (ph >= 1 && ph <= 32) {     // GEMM on spikes of phase ph-1
                const _Float16* sb = &spk[(ph - 1) & 1][0][0];
                half8 B0[12], B1[12];
#pragma unroll
                for (int kt = 0; kt < 12; ++kt) {
                    B0[kt] = *(const half8*)(sb + nL * SPKW + kt * 32 + q * 8);
                    B1[kt] = *(const half8*)(sb + (16 + nL) * SPKW + kt * 32 + q * 8);
                }
                f32x4 acc0 = {0.f, 0.f, 0.f, 0.f};
                f32x4 acc1 = {0.f, 0.f, 0.f, 0.f};
#pragma unroll
                for (int kt = 0; kt < 12; ++kt) {
                    acc0 = __builtin_amdgcn_mfma_f32_16x16x32_f16(A[kt], B0[kt], acc0, 0, 0, 0);
                    acc1 = __builtin_amdgcn_mfma_f32_16x16x32_f16(A[kt], B1[kt], acc1, 0, 0, 0);
                }
                // C/D: col = lane&15 (t_local), row = q*4+i (o_local)
                float* cd = &c2L[(ph - 1) & 1][0][0];
                *(f32x4*)(cd + nL * C2W + m * 16 + q * 4)        = acc0;
                *(f32x4*)(cd + (16 + nL) * C2W + m * 16 + q * 4) = acc1;
            }
            if (wid == 3 && lane < 35 && ph >= 2) {   // LIF2 scan of phase ph-2
                const float* cs = &c2L[(ph - 2) & 1][0][0];
                const int tb = (ph - 2) * SPH;
#pragma unroll
                for (int s8 = 0; s8 < SPH; s8 += 8) {
                    float v[8];
#pragma unroll
                    for (int j = 0; j < 8; ++j) v[j] = cs[(s8 + j) * C2W + lane] + fcb;
#pragma unroll
                    for (int j = 0; j < 8; ++j) {
                        float r2 = (mem2 > 1.0f) ? 1.0f : 0.0f;
                        mem2 = 0.9f * mem2 + v[j] - r2;
                        if (tb + s8 + j < TN) accO += mem2;
                    }
                }
            }
        }
        __syncthreads();
    }

    if (wid == 3 && lane < 35) out[b * 35 + lane] = accO * (1.0f / (float)TN);
}

extern "C" void kernel_launch(void* const* d_in, const int* in_sizes, int n_in,
                              void* d_out, int out_size, void* d_ws, size_t ws_size,
                              hipStream_t stream) {
    const float* x      = (const float*)d_in[0];
    const float* conv_w = (const float*)d_in[1];
    const float* conv_b = (const float*)d_in[2];
    const float* fc_w   = (const float*)d_in[3];
    const float* fc_b   = (const float*)d_in[4];
    float* out          = (float*)d_out;

    snn_fwd<<<256, 384, 0, stream>>>(x, conv_w, conv_b, fc_w, fc_b, out);
}

// Round 6
// 168.850 us; speedup vs baseline: 3.3847x; 1.0014x over previous
//
#include <hip/hip_runtime.h>

typedef _Float16 half8 __attribute__((ext_vector_type(8)));
typedef float f32x4 __attribute__((ext_vector_type(4)));

#define SPH  32           // timesteps per phase
#define NIT  34           // 32 compute phases + 2 pipeline-drain iterations
#define SPKW 392          // spk row stride f16: 384 + 8 pad (784 B rows; +4 banks/row)
#define XSW  32           // xs row stride (floats)
#define C2W  48           // c2L row stride (floats); wave m=2 writes cols 32..47
#define TN   1000

// Software-pipelined, ONE barrier per iteration. At iteration ph:
//   waves 0-2: conv+LIF1(ph)  [reads xs[ph&1], writes spk[ph&1]] + stage xs(ph+1)
//   waves 3-5: FC GEMM(ph-1)  [reads spk[(ph-1)&1], writes c2L[(ph-1)&1]]
//   wave 3:    LIF2 scan(ph-2) [reads c2L[(ph-2)&1]] -- loads hoisted BEFORE MFMA
// Conv loop uses explicit register prefetch (4-step chunks, ping-pong) to hide
// ds_read latency; launch_bounds(384,1) lifts the VGPR cap so the x data stays
// in registers.
__global__ __launch_bounds__(384, 1) void snn_fwd(
    const float* __restrict__ x,      // (256,1000,30)
    const float* __restrict__ conv_w, // (16,1,7)
    const float* __restrict__ conv_b, // (16)
    const float* __restrict__ fc_w,   // (35,384)
    const float* __restrict__ fc_b,   // (35)
    float* __restrict__ out)          // (256,35)
{
    __shared__ _Float16 spk[2][SPH][SPKW];   // 50176 B
    __shared__ float    xs[2][SPH][XSW];     //  8192 B
    __shared__ float    c2L[2][SPH][C2W];    // 12288 B

    const int tid  = threadIdx.x;
    const int b    = blockIdx.x;
    const int wid  = tid >> 6;
    const int lane = tid & 63;

    // ---------- conv-wave setup: thread = (c=ct/12, u=ct%12) -> positions 2u,2u+1 ----------
    const int ct = tid;          // 0..191 when wid<3
    const int c  = ct / 12;
    const int u  = ct % 12;
    float wk[7];
    float cb = 0.f;
    if (wid < 3) {
#pragma unroll
        for (int k = 0; k < 7; ++k) wk[k] = conv_w[c * 7 + k];
        cb = conv_b[c];
    }

    // ---------- FC-wave setup: A fragments (f16 weights, K=384) ----------
    const int m  = wid - 3;
    const int nL = lane & 15;    // B col (t_local); C col
    const int q  = lane >> 4;    // quad: k = q*8 + j
    half8 A[12];
    if (wid >= 3) {
        const int o = m * 16 + nL;
#pragma unroll
        for (int kt = 0; kt < 12; ++kt) {
            half8 a;
#pragma unroll
            for (int j = 0; j < 8; ++j) {
                int K = kt * 32 + q * 8 + j;
                a[j] = (o < 35) ? (_Float16)fc_w[o * 384 + K] : (_Float16)0.f;
            }
            A[kt] = a;
        }
    }
    const float fcb = (wid == 3 && lane < 35) ? fc_b[lane] : 0.f;

    // ---------- state ----------
    float m10 = 0.f, m11 = 0.f, sp0 = 0.f, sp1 = 0.f;   // LIF1
    float mem2 = 0.f, accO = 0.f;                        // LIF2 (wave3 lanes<35)

    const float* xb = x + (size_t)b * (TN * 30);

    // ---------- prologue: stage xs[0] (960 floats = 192 thr * 5) ----------
    if (wid < 3) {
#pragma unroll
        for (int r = 0; r < 5; ++r) {
            int f = ct + 192 * r;          // 0..959
            xs[0][f / 30][f % 30] = xb[f]; // t < 32 < TN
        }
    }
    __syncthreads();

#pragma unroll 1
    for (int ph = 0; ph < NIT; ++ph) {
        if (wid < 3) {
            float xr[5];
            const bool stg = (ph <= 30);
            if (stg) {                     // issue global loads early (latency overlap)
                const float* src = xb + (ph + 1) * (SPH * 30);
#pragma unroll
                for (int r = 0; r < 5; ++r) {
                    int f = ct + 192 * r;
                    int t = (ph + 1) * SPH + f / 30;
                    xr[r] = (t < TN) ? src[f] : 0.f;
                }
            }
            if (ph < 32) {
                const float* xrow = &xs[ph & 1][0][2 * u];
                _Float16* sdst = &spk[ph & 1][0][2 * ct];

                float2 XA[4][4], XB[4][4];

#define LOADC(X, CH)                                                          \
                {                                                             \
                    _Pragma("unroll")                                         \
                    for (int s = 0; s < 4; ++s) {                             \
                        const float2* x2 =                                    \
                            (const float2*)(xrow + ((CH) * 4 + s) * XSW);     \
                        X[s][0] = x2[0]; X[s][1] = x2[1];                     \
                        X[s][2] = x2[2]; X[s][3] = x2[3];                     \
                    }                                                         \
                }

#define COMPC(X, CH)                                                          \
                {                                                             \
                    _Pragma("unroll")                                         \
                    for (int s = 0; s < 4; ++s) {                             \
                        float2 a0 = X[s][0], a1 = X[s][1];                    \
                        float2 a2 = X[s][2], a3 = X[s][3];                    \
                        float c1a = cb, c1b = cb;                             \
                        c1a = fmaf(wk[0], a0.x, c1a);  c1b = fmaf(wk[0], a0.y, c1b); \
                        c1a = fmaf(wk[1], a0.y, c1a);  c1b = fmaf(wk[1], a1.x, c1b); \
                        c1a = fmaf(wk[2], a1.x, c1a);  c1b = fmaf(wk[2], a1.y, c1b); \
                        c1a = fmaf(wk[3], a1.y, c1a);  c1b = fmaf(wk[3], a2.x, c1b); \
                        c1a = fmaf(wk[4], a2.x, c1a);  c1b = fmaf(wk[4], a2.y, c1b); \
                        c1a = fmaf(wk[5], a2.y, c1a);  c1b = fmaf(wk[5], a3.x, c1b); \
                        c1a = fmaf(wk[6], a3.x, c1a);  c1b = fmaf(wk[6], a3.y, c1b); \
                        m10 = fmaf(0.9f, m10, c1a - sp0);                     \
                        m11 = fmaf(0.9f, m11, c1b - sp1);                     \
                        sp0 = (m10 > 1.0f) ? 1.0f : 0.0f;                     \
                        sp1 = (m11 > 1.0f) ? 1.0f : 0.0f;                     \
                        unsigned pk = (m10 > 1.0f ? 0x3C00u : 0u) |           \
                                      (m11 > 1.0f ? 0x3C000000u : 0u);        \
                        *(unsigned*)(sdst + ((CH) * 4 + s) * SPKW) = pk;      \
                    }                                                         \
                }

                LOADC(XA, 0)
#pragma unroll 1
                for (int chn = 0; chn < 8; chn += 2) {
                    if (chn + 1 < 8) LOADC(XB, chn + 1)
                    COMPC(XA, chn)
                    if (chn + 2 < 8) LOADC(XA, chn + 2)
                    COMPC(XB, chn + 1)
                }
#undef LOADC
#undef COMPC
            }
            if (stg) {                     // store staged x into the other buffer
                float* dst = &xs[(ph + 1) & 1][0][0];
#pragma unroll
                for (int r = 0; r < 5; ++r) {
                    int f = ct + 192 * r;
                    dst[(f / 30) * XSW + (f % 30)] = xr[r];
                }
            }
        } else {
            // ---- scan loads hoisted: issue before GEMM so the scan chain
            //      overlaps the MFMA pipe instead of following it ----
            const bool doScan = (wid == 3 && lane < 35 && ph >= 2);
            float v[SPH];
            if (doScan) {
                const float* cs = &c2L[(ph - 2) & 1][0][0];
#pragma unroll
                for (int j = 0; j < SPH; ++j) v[j] = cs[j * C2W + lane];
            }
            if (ph >= 1 && ph <= 32) {     // GEMM on spikes of phase ph-1
                const _Float16* sb = &spk[(ph - 1) & 1][0][0];
                half8 B0[12], B1[12];
#pragma unroll
                for (int kt = 0; kt < 12; ++kt) {
                    B0[kt] = *(const half8*)(sb + nL * SPKW + kt * 32 + q * 8);
                    B1[kt] = *(const half8*)(sb + (16 + nL) * SPKW + kt * 32 + q * 8);
                }
                f32x4 acc0 = {0.f, 0.f, 0.f, 0.f};
                f32x4 acc1 = {0.f, 0.f, 0.f, 0.f};
#pragma unroll
                for (int kt = 0; kt < 12; ++kt) {
                    acc0 = __builtin_amdgcn_mfma_f32_16x16x32_f16(A[kt], B0[kt], acc0, 0, 0, 0);
                    acc1 = __builtin_amdgcn_mfma_f32_16x16x32_f16(A[kt], B1[kt], acc1, 0, 0, 0);
                }
                // C/D: col = lane&15 (t_local), row = q*4+i (o_local)
                float* cd = &c2L[(ph - 1) & 1][0][0];
                *(f32x4*)(cd + nL * C2W + m * 16 + q * 4)        = acc0;
                *(f32x4*)(cd + (16 + nL) * C2W + m * 16 + q * 4) = acc1;
            }
            if (doScan) {                  // LIF2 scan of phase ph-2
                const int tb = (ph - 2) * SPH;
#pragma unroll
                for (int j = 0; j < SPH; ++j) {
                    float r2 = (mem2 > 1.0f) ? 1.0f : 0.0f;
                    mem2 = 0.9f * mem2 + (v[j] + fcb) - r2;
                    if (tb + j < TN) accO += mem2;
                }
            }
        }
        __syncthreads();
    }

    if (wid == 3 && lane < 35) out[b * 35 + lane] = accO * (1.0f / (float)TN);
}

extern "C" void kernel_launch(void* const* d_in, const int* in_sizes, int n_in,
                              void* d_out, int out_size, void* d_ws, size_t ws_size,
                              hipStream_t stream) {
    const float* x      = (const float*)d_in[0];
    const float* conv_w = (const float*)d_in[1];
    const float* conv_b = (const float*)d_in[2];
    const float* fc_w   = (const float*)d_in[3];
    const float* fc_b   = (const float*)d_in[4];
    float* out          = (float*)d_out;

    snn_fwd<<<256, 384, 0, stream>>>(x, conv_w, conv_b, fc_w, fc_b, out);
}